// Round 3
// baseline (257.032 us; speedup 1.0000x reference)
//
#include <hip/hip_runtime.h>
#include <hip/hip_bf16.h>

typedef __attribute__((ext_vector_type(8))) short short8;
typedef __attribute__((ext_vector_type(4))) float f32x4;

constexpr int BATCH  = 4;
constexpr int NSRC   = 2048;
constexpr int NTGT   = 8192;
constexpr int C_IN   = 256;
constexpr int C_SKIP = 128;
constexpr int DIN    = 384;   // C_IN + C_SKIP
constexpr int HID    = 256;
constexpr int MROWS  = BATCH * NTGT;  // 32768

constexpr int TGT_PER_BLK = 8;
constexpr int KNN_BLOCKS  = MROWS / TGT_PER_BLK;  // 4096
constexpr int WT_BLOCKS   = 8;                    // W1 transpose helper blocks
constexpr int GEMM_BLOCKS = 256;                  // persistent, 1/CU guaranteed-resident

// ================= fused KNN + interpolate + concat (+W1 transpose, +zeroing) =================
// blocks [0, KNN_BLOCKS): 8 targets each; 32 lanes/target scan 64 sources; butterfly merge;
//   then gather 3 feature rows + skip and write H0 (bf16).
// blocks [KNN_BLOCKS, KNN_BLOCKS+8): transpose W1 -> W1T bf16.
// block KNN_BLOCKS+8: zero stats + grid-barrier counter.
__global__ __launch_bounds__(256) void knn_h_kernel(const float* __restrict__ pos,
                                                    const float* __restrict__ pos_skip,
                                                    const float* __restrict__ x,
                                                    const float* __restrict__ xs,
                                                    const float* __restrict__ W1,
                                                    __hip_bfloat16* __restrict__ W1T,
                                                    __hip_bfloat16* __restrict__ H0,
                                                    float* __restrict__ stats,
                                                    int* __restrict__ barrier_ct) {
    const int blk = blockIdx.x;
    if (blk >= KNN_BLOCKS) {
        const int e = blk - KNN_BLOCKS;
        if (e < WT_BLOCKS) {
            const int r = e * 32 + (threadIdx.x >> 3);   // W1T row (output channel)
            const int c0 = threadIdx.x & 7;
#pragma unroll
            for (int k = 0; k < DIN / 8; ++k) {
                int c = c0 + k * 8;
                W1T[(size_t)r * DIN + c] = __float2bfloat16(W1[(size_t)c * HID + r]);
            }
        } else {
            for (int i = threadIdx.x; i < 4 * HID; i += 256) stats[i] = 0.0f;
            if (threadIdx.x == 0) *barrier_ct = 0;
        }
        return;
    }
    __shared__ float4 sp[NSRC];
    __shared__ float  sd[TGT_PER_BLK][3];
    __shared__ int    si[TGT_PER_BLK][3];
    const int t0 = blk * TGT_PER_BLK;
    const int b  = t0 / NTGT;
    const float* ps = pos + (size_t)b * NSRC * 3;
    for (int j = threadIdx.x; j < NSRC; j += 256) {
        float X = ps[j * 3 + 0], Y = ps[j * 3 + 1], Z = ps[j * 3 + 2];
        float s2 = __fadd_rn(__fadd_rn(__fmul_rn(X, X), __fmul_rn(Y, Y)), __fmul_rn(Z, Z));
        sp[j] = make_float4(X, Y, Z, s2);
    }
    __syncthreads();
    const int g  = threadIdx.x >> 5;   // target group 0..7
    const int s  = threadIdx.x & 31;   // sub-lane 0..31
    const int tr = t0 + g;
    const float px = pos_skip[tr * 3 + 0], py = pos_skip[tr * 3 + 1], pz = pos_skip[tr * 3 + 2];
    const float pt2 = __fadd_rn(__fadd_rn(__fmul_rn(px, px), __fmul_rn(py, py)), __fmul_rn(pz, pz));
    float bd0 = 3e38f, bd1 = 3e38f, bd2 = 3e38f;
    int   bi0 = 0x7fffffff, bi1 = 0x7fffffff, bi2 = 0x7fffffff;
#pragma unroll 8
    for (int k = 0; k < NSRC / 32; ++k) {
        const int j = k * 32 + s;
        float4 sv = sp[j];
        // exact replica of reference's expanded formula: (pt2 + ps2) - 2*dot, no FMA
        float dot = __fadd_rn(__fadd_rn(__fmul_rn(px, sv.x), __fmul_rn(py, sv.y)), __fmul_rn(pz, sv.z));
        float d2  = __fsub_rn(__fadd_rn(pt2, sv.w), __fmul_rn(2.0f, dot));
        bool c0 = d2 < bd0, c1 = d2 < bd1, c2 = d2 < bd2;
        bd2 = c1 ? bd1 : (c2 ? d2 : bd2);  bi2 = c1 ? bi1 : (c2 ? j : bi2);
        bd1 = c0 ? bd0 : (c1 ? d2 : bd1);  bi1 = c0 ? bi0 : (c1 ? j : bi1);
        bd0 = c0 ? d2  : bd0;              bi0 = c0 ? j  : bi0;
    }
    // butterfly merge across 32 sub-lanes; lex (d, idx) preserves reference tie-break
#pragma unroll
    for (int m = 1; m <= 16; m <<= 1) {
        float od0 = __shfl_xor(bd0, m), od1 = __shfl_xor(bd1, m), od2 = __shfl_xor(bd2, m);
        int   oi0 = __shfl_xor(bi0, m), oi1 = __shfl_xor(bi1, m), oi2 = __shfl_xor(bi2, m);
#pragma unroll
        for (int e = 0; e < 3; ++e) {
            float d = e == 0 ? od0 : (e == 1 ? od1 : od2);
            int   i = e == 0 ? oi0 : (e == 1 ? oi1 : oi2);
            bool c0 = (d < bd0) || (d == bd0 && i < bi0);
            bool c1 = (d < bd1) || (d == bd1 && i < bi1);
            bool c2 = (d < bd2) || (d == bd2 && i < bi2);
            bd2 = c1 ? bd1 : (c2 ? d : bd2);  bi2 = c1 ? bi1 : (c2 ? i : bi2);
            bd1 = c0 ? bd0 : (c1 ? d : bd1);  bi1 = c0 ? bi0 : (c1 ? i : bi1);
            bd0 = c0 ? d   : bd0;             bi0 = c0 ? i  : bi0;
        }
    }
    if (s == 0) {
        sd[g][0] = bd0; sd[g][1] = bd1; sd[g][2] = bd2;
        si[g][0] = bi0; si[g][1] = bi1; si[g][2] = bi2;
    }
    __syncthreads();
    // gather + concat phase: 4 waves x 2 targets, 64-lane coalesced columns
    const int w = threadIdx.x >> 6, lane = threadIdx.x & 63;
    const float* xb = x + (size_t)b * NSRC * C_IN;
#pragma unroll
    for (int u = 0; u < 2; ++u) {
        const int tt = w * 2 + u;
        const int r  = t0 + tt;
        float w0 = 1.0f / fmaxf(sd[tt][0], 1e-16f);
        float w1 = 1.0f / fmaxf(sd[tt][1], 1e-16f);
        float w2 = 1.0f / fmaxf(sd[tt][2], 1e-16f);
        float inv = 1.0f / ((w0 + w1) + w2);
        const float* f0 = xb + (size_t)si[tt][0] * C_IN;
        const float* f1 = xb + (size_t)si[tt][1] * C_IN;
        const float* f2 = xb + (size_t)si[tt][2] * C_IN;
        __hip_bfloat16* o = H0 + (size_t)r * DIN;
#pragma unroll
        for (int kk = 0; kk < 4; ++kk) {
            int c = lane + kk * 64;
            float v = ((w0 * f0[c] + w1 * f1[c]) + w2 * f2[c]) * inv;
            o[c] = __float2bfloat16(v);
        }
        const float* srow = xs + (size_t)r * C_SKIP;
#pragma unroll
        for (int kk = 0; kk < 2; ++kk) {
            int c = lane + kk * 64;
            o[C_IN + c] = __float2bfloat16(srow[c]);
        }
    }
}

// ================= GEMM template: out = relu(A@W + bias), column stats; COOP fuses BN =================
// A: [MROWS][K] bf16; WT: [HID][K] bf16. 512 thr = 8 waves (2 row-halves x 4 col-quarters),
// block covers 128 rows x all 256 cols. COOP: atomics -> grid barrier -> BN applied in-register.
template <int K, bool OUT_BF16, bool COOP>
__global__ __launch_bounds__(512) void gemm_kernel(const __hip_bfloat16* __restrict__ A,
                                                   const __hip_bfloat16* __restrict__ WT,
                                                   const float* __restrict__ bias,
                                                   void* __restrict__ outp,
                                                   float* __restrict__ colsum,
                                                   float* __restrict__ colsq,
                                                   const float* __restrict__ g,
                                                   const float* __restrict__ be,
                                                   int* __restrict__ barrier_ct) {
    __shared__ short As[128 * 40];  // 128 rows x 32 cols bf16, padded stride 40
    const int t = threadIdx.x;
    const int m0 = blockIdx.x * 128;
    const int wid = t >> 6, lane = t & 63;
    const int wr = wid >> 2, wc = wid & 3;
    const int l15 = lane & 15, l4 = lane >> 4;
    const int arow = t >> 2, acol8 = (t & 3) * 8;
    f32x4 acc[4][4] = {};
    const short* Ash = (const short*)A;
    const short* Wsh = (const short*)WT;
    for (int kt = 0; kt < K / 32; ++kt) {
        short8 v = *(const short8*)(Ash + (size_t)(m0 + arow) * K + kt * 32 + acol8);
        __syncthreads();
        *(short8*)(&As[arow * 40 + acol8]) = v;
        __syncthreads();
        short8 af[4], bfr[4];
#pragma unroll
        for (int mi = 0; mi < 4; ++mi)
            af[mi] = *(const short8*)(&As[(wr * 64 + mi * 16 + l15) * 40 + l4 * 8]);
#pragma unroll
        for (int ni = 0; ni < 4; ++ni)
            bfr[ni] = *(const short8*)(Wsh + (size_t)(wc * 64 + ni * 16 + l15) * K + kt * 32 + l4 * 8);
#pragma unroll
        for (int mi = 0; mi < 4; ++mi)
#pragma unroll
            for (int ni = 0; ni < 4; ++ni)
                acc[mi][ni] = __builtin_amdgcn_mfma_f32_16x16x32_bf16(af[mi], bfr[ni], acc[mi][ni], 0, 0, 0);
    }
    float bv[4];
    int col[4];
#pragma unroll
    for (int ni = 0; ni < 4; ++ni) {
        col[ni] = wc * 64 + ni * 16 + l15;
        bv[ni] = bias[col[ni]];
    }
    float csum[4] = {0, 0, 0, 0}, csq[4] = {0, 0, 0, 0};
    __hip_bfloat16* ob = (__hip_bfloat16*)outp;
    float* of = (float*)outp;
#pragma unroll
    for (int mi = 0; mi < 4; ++mi) {
#pragma unroll
        for (int r = 0; r < 4; ++r) {
            int rowg = m0 + wr * 64 + mi * 16 + l4 * 4 + r;
#pragma unroll
            for (int ni = 0; ni < 4; ++ni) {
                float v = fmaxf(acc[mi][ni][r] + bv[ni], 0.0f);
                if (!COOP) {
                    if (OUT_BF16) ob[(size_t)rowg * HID + col[ni]] = __float2bfloat16(v);
                    else          of[(size_t)rowg * HID + col[ni]] = v;
                }
                csum[ni] += v;
                csq[ni] += v * v;
            }
        }
    }
#pragma unroll
    for (int ni = 0; ni < 4; ++ni) {
        float sv = csum[ni], q = csq[ni];
        sv += __shfl_xor(sv, 16); sv += __shfl_xor(sv, 32);
        q  += __shfl_xor(q, 16);  q  += __shfl_xor(q, 32);
        if (l4 == 0) {
            atomicAdd(&colsum[col[ni]], sv);
            atomicAdd(&colsq[col[ni]], q);
        }
    }
    if (COOP) {
        // grid barrier: 256 blocks, guaranteed co-resident (8 waves/CU, 10KB LDS, 1/CU)
        __syncthreads();
        if (t == 0) {
            __threadfence();
            __hip_atomic_fetch_add(barrier_ct, 1, __ATOMIC_ACQ_REL, __HIP_MEMORY_SCOPE_AGENT);
            while (__hip_atomic_load(barrier_ct, __ATOMIC_ACQUIRE, __HIP_MEMORY_SCOPE_AGENT) < GEMM_BLOCKS) {}
            __threadfence();
        }
        __syncthreads();
        float sc2[4], sh2[4];
#pragma unroll
        for (int ni = 0; ni < 4; ++ni) {
            float sm = __hip_atomic_load(&colsum[col[ni]], __ATOMIC_ACQUIRE, __HIP_MEMORY_SCOPE_AGENT);
            float qq = __hip_atomic_load(&colsq[col[ni]],  __ATOMIC_ACQUIRE, __HIP_MEMORY_SCOPE_AGENT);
            float mu  = sm * (1.0f / MROWS);
            float var = qq * (1.0f / MROWS) - mu * mu;
            float scv = g[col[ni]] / sqrtf(var + 1e-5f);
            sc2[ni] = scv;
            sh2[ni] = be[col[ni]] - mu * scv;
        }
#pragma unroll
        for (int mi = 0; mi < 4; ++mi)
#pragma unroll
            for (int r = 0; r < 4; ++r) {
                int rowg = m0 + wr * 64 + mi * 16 + l4 * 4 + r;
#pragma unroll
                for (int ni = 0; ni < 4; ++ni) {
                    float v = fmaxf(acc[mi][ni][r] + bv[ni], 0.0f);
                    of[(size_t)rowg * HID + col[ni]] = sc2[ni] * v + sh2[ni];
                }
            }
    }
}

// ================= finalize BN1 + fold into W2 (absorbs old finalize_kernel) =================
__global__ __launch_bounds__(256) void foldw2_kernel(const float* __restrict__ W2,
                                                     const float* __restrict__ b2,
                                                     const float* __restrict__ sum1,
                                                     const float* __restrict__ sq1,
                                                     const float* __restrict__ g1,
                                                     const float* __restrict__ be1,
                                                     __hip_bfloat16* __restrict__ W2T,
                                                     float* __restrict__ bias2f) {
    __shared__ float red[256];
    const int n = blockIdx.x, k = threadIdx.x;
    float mu  = sum1[k] * (1.0f / MROWS);
    float var = sq1[k] * (1.0f / MROWS) - mu * mu;
    float scv = g1[k] / sqrtf(var + 1e-5f);
    float shv = be1[k] - mu * scv;
    float v = W2[(size_t)k * HID + n];
    W2T[(size_t)n * HID + k] = __float2bfloat16(scv * v);
    red[k] = shv * v;
    __syncthreads();
    for (int s = 128; s > 0; s >>= 1) {
        if (k < s) red[k] += red[k + s];
        __syncthreads();
    }
    if (k == 0) bias2f[n] = b2[n] + red[0];
}

extern "C" void kernel_launch(void* const* d_in, const int* in_sizes, int n_in,
                              void* d_out, int out_size, void* d_ws, size_t ws_size,
                              hipStream_t stream) {
    const float* x    = (const float*)d_in[0];
    const float* pos  = (const float*)d_in[1];
    const float* xs   = (const float*)d_in[3];
    const float* poss = (const float*)d_in[4];
    const float* W1   = (const float*)d_in[6];
    const float* b1   = (const float*)d_in[7];
    const float* g1   = (const float*)d_in[8];
    const float* be1  = (const float*)d_in[9];
    const float* W2   = (const float*)d_in[10];
    const float* b2   = (const float*)d_in[11];
    const float* g2   = (const float*)d_in[12];
    const float* be2  = (const float*)d_in[13];

    char* ws = (char*)d_ws;
    size_t off = 0;
    auto alloc = [&](size_t bytes) -> void* {
        void* p = ws + off;
        off += (bytes + 255) & ~(size_t)255;
        return p;
    };
    __hip_bfloat16* W1T   = (__hip_bfloat16*)alloc((size_t)HID * DIN * 2);
    __hip_bfloat16* W2T   = (__hip_bfloat16*)alloc((size_t)HID * HID * 2);
    float*          stats = (float*)alloc(4 * HID * sizeof(float));
    float *sum1 = stats, *sq1 = stats + HID, *sum2 = stats + 2 * HID, *sq2 = stats + 3 * HID;
    float*          bias2f = (float*)alloc(HID * sizeof(float));
    int*            barrier_ct = (int*)alloc(sizeof(int));
    __hip_bfloat16* H0 = (__hip_bfloat16*)alloc((size_t)MROWS * DIN * 2);
    __hip_bfloat16* H1 = (__hip_bfloat16*)alloc((size_t)MROWS * HID * 2);

    knn_h_kernel<<<KNN_BLOCKS + WT_BLOCKS + 1, 256, 0, stream>>>(pos, poss, x, xs, W1, W1T, H0,
                                                                 stats, barrier_ct);
    gemm_kernel<DIN, true, false><<<GEMM_BLOCKS, 512, 0, stream>>>(H0, W1T, b1, H1, sum1, sq1,
                                                                   g1, be1, barrier_ct);
    foldw2_kernel<<<HID, 256, 0, stream>>>(W2, b2, sum1, sq1, g1, be1, W2T, bias2f);
    gemm_kernel<HID, false, true><<<GEMM_BLOCKS, 512, 0, stream>>>(H1, W2T, bias2f, d_out, sum2, sq2,
                                                                   g2, be2, barrier_ct);
}

// Round 4
// 144.702 us; speedup vs baseline: 1.7763x; 1.7763x over previous
//
#include <hip/hip_runtime.h>
#include <hip/hip_bf16.h>

typedef __attribute__((ext_vector_type(8))) short short8;
typedef __attribute__((ext_vector_type(4))) float f32x4;

constexpr int BATCH  = 4;
constexpr int NSRC   = 2048;
constexpr int NTGT   = 8192;
constexpr int C_IN   = 256;
constexpr int C_SKIP = 128;
constexpr int DIN    = 384;   // C_IN + C_SKIP
constexpr int HID    = 256;
constexpr int MROWS  = BATCH * NTGT;  // 32768

constexpr int TGT_PER_BLK = 8;
constexpr int KNN_BLOCKS  = MROWS / TGT_PER_BLK;  // 4096
constexpr int WT_BLOCKS   = 8;                    // W1 transpose helper blocks
constexpr int LDS_STRIDE  = 36;                   // A-tile pad: 18*l15 mod 32 hits all even banks

// ================= fused KNN + interpolate + concat (+W1 transpose, +stats zero) =================
__global__ __launch_bounds__(256) void knn_h_kernel(const float* __restrict__ pos,
                                                    const float* __restrict__ pos_skip,
                                                    const float* __restrict__ x,
                                                    const float* __restrict__ xs,
                                                    const float* __restrict__ W1,
                                                    __hip_bfloat16* __restrict__ W1T,
                                                    __hip_bfloat16* __restrict__ H0,
                                                    float* __restrict__ stats) {
    const int blk = blockIdx.x;
    if (blk >= KNN_BLOCKS) {
        const int e = blk - KNN_BLOCKS;
        if (e < WT_BLOCKS) {
            const int r = e * 32 + (threadIdx.x >> 3);   // W1T row (output channel)
            const int c0 = threadIdx.x & 7;
#pragma unroll
            for (int k = 0; k < DIN / 8; ++k) {
                int c = c0 + k * 8;
                W1T[(size_t)r * DIN + c] = __float2bfloat16(W1[(size_t)c * HID + r]);
            }
        } else {
            for (int i = threadIdx.x; i < 4 * HID; i += 256) stats[i] = 0.0f;
        }
        return;
    }
    __shared__ float4 sp[NSRC];
    __shared__ float  sd[TGT_PER_BLK][3];
    __shared__ int    si[TGT_PER_BLK][3];
    const int t0 = blk * TGT_PER_BLK;
    const int b  = t0 / NTGT;
    const float* ps = pos + (size_t)b * NSRC * 3;
    for (int j = threadIdx.x; j < NSRC; j += 256) {
        float X = ps[j * 3 + 0], Y = ps[j * 3 + 1], Z = ps[j * 3 + 2];
        float s2 = __fadd_rn(__fadd_rn(__fmul_rn(X, X), __fmul_rn(Y, Y)), __fmul_rn(Z, Z));
        sp[j] = make_float4(X, Y, Z, s2);
    }
    __syncthreads();
    const int g  = threadIdx.x >> 5;   // target group 0..7
    const int s  = threadIdx.x & 31;   // sub-lane 0..31
    const int tr = t0 + g;
    const float px = pos_skip[tr * 3 + 0], py = pos_skip[tr * 3 + 1], pz = pos_skip[tr * 3 + 2];
    const float pt2 = __fadd_rn(__fadd_rn(__fmul_rn(px, px), __fmul_rn(py, py)), __fmul_rn(pz, pz));
    float bd0 = 3e38f, bd1 = 3e38f, bd2 = 3e38f;
    int   bi0 = 0x7fffffff, bi1 = 0x7fffffff, bi2 = 0x7fffffff;
#pragma unroll 8
    for (int k = 0; k < NSRC / 32; ++k) {
        const int j = k * 32 + s;
        float4 sv = sp[j];
        // exact replica of reference's expanded formula: (pt2 + ps2) - 2*dot, no FMA
        float dot = __fadd_rn(__fadd_rn(__fmul_rn(px, sv.x), __fmul_rn(py, sv.y)), __fmul_rn(pz, sv.z));
        float d2  = __fsub_rn(__fadd_rn(pt2, sv.w), __fmul_rn(2.0f, dot));
        bool c0 = d2 < bd0, c1 = d2 < bd1, c2 = d2 < bd2;
        bd2 = c1 ? bd1 : (c2 ? d2 : bd2);  bi2 = c1 ? bi1 : (c2 ? j : bi2);
        bd1 = c0 ? bd0 : (c1 ? d2 : bd1);  bi1 = c0 ? bi0 : (c1 ? j : bi1);
        bd0 = c0 ? d2  : bd0;              bi0 = c0 ? j  : bi0;
    }
    // butterfly merge across 32 sub-lanes; lex (d, idx) preserves reference tie-break
#pragma unroll
    for (int m = 1; m <= 16; m <<= 1) {
        float od0 = __shfl_xor(bd0, m), od1 = __shfl_xor(bd1, m), od2 = __shfl_xor(bd2, m);
        int   oi0 = __shfl_xor(bi0, m), oi1 = __shfl_xor(bi1, m), oi2 = __shfl_xor(bi2, m);
#pragma unroll
        for (int e = 0; e < 3; ++e) {
            float d = e == 0 ? od0 : (e == 1 ? od1 : od2);
            int   i = e == 0 ? oi0 : (e == 1 ? oi1 : oi2);
            bool c0 = (d < bd0) || (d == bd0 && i < bi0);
            bool c1 = (d < bd1) || (d == bd1 && i < bi1);
            bool c2 = (d < bd2) || (d == bd2 && i < bi2);
            bd2 = c1 ? bd1 : (c2 ? d : bd2);  bi2 = c1 ? bi1 : (c2 ? i : bi2);
            bd1 = c0 ? bd0 : (c1 ? d : bd1);  bi1 = c0 ? bi0 : (c1 ? i : bi1);
            bd0 = c0 ? d   : bd0;             bi0 = c0 ? i  : bi0;
        }
    }
    if (s == 0) {
        sd[g][0] = bd0; sd[g][1] = bd1; sd[g][2] = bd2;
        si[g][0] = bi0; si[g][1] = bi1; si[g][2] = bi2;
    }
    __syncthreads();
    // gather + concat phase: 4 waves x 2 targets, 64-lane coalesced columns
    const int w = threadIdx.x >> 6, lane = threadIdx.x & 63;
    const float* xb = x + (size_t)b * NSRC * C_IN;
#pragma unroll
    for (int u = 0; u < 2; ++u) {
        const int tt = w * 2 + u;
        const int r  = t0 + tt;
        float w0 = 1.0f / fmaxf(sd[tt][0], 1e-16f);
        float w1 = 1.0f / fmaxf(sd[tt][1], 1e-16f);
        float w2 = 1.0f / fmaxf(sd[tt][2], 1e-16f);
        float inv = 1.0f / ((w0 + w1) + w2);
        const float* f0 = xb + (size_t)si[tt][0] * C_IN;
        const float* f1 = xb + (size_t)si[tt][1] * C_IN;
        const float* f2 = xb + (size_t)si[tt][2] * C_IN;
        __hip_bfloat16* o = H0 + (size_t)r * DIN;
#pragma unroll
        for (int kk = 0; kk < 4; ++kk) {
            int c = lane + kk * 64;
            float v = ((w0 * f0[c] + w1 * f1[c]) + w2 * f2[c]) * inv;
            o[c] = __float2bfloat16(v);
        }
        const float* srow = xs + (size_t)r * C_SKIP;
#pragma unroll
        for (int kk = 0; kk < 2; ++kk) {
            int c = lane + kk * 64;
            o[C_IN + c] = __float2bfloat16(srow[c]);
        }
    }
}

// ================= GEMM: out = relu(A@W + bias), plus column sum/sumsq =================
// A: [MROWS][K] bf16; WT: [HID][K] bf16. 256 thr = 4 waves (2x2), 128x128 tile.
// __launch_bounds__(256, 2): VGPR cap 256 -> acc[4][4] (64 VGPRs) stays in registers (R3
// regression: unconstrained 512-thr block allocated 60 VGPRs and spilled acc to scratch).
template <int K, bool OUT_BF16>
__global__ __launch_bounds__(256, 2) void gemm_kernel(const __hip_bfloat16* __restrict__ A,
                                                      const __hip_bfloat16* __restrict__ WT,
                                                      const float* __restrict__ bias,
                                                      void* __restrict__ outp,
                                                      float* __restrict__ colsum,
                                                      float* __restrict__ colsq) {
    __shared__ short As[128 * LDS_STRIDE];  // 128 rows x 32 cols bf16, padded stride 36
    const int t = threadIdx.x;
    const int m0 = blockIdx.x * 128, n0 = blockIdx.y * 128;
    const int wid = t >> 6, lane = t & 63;
    const int wr = wid >> 1, wc = wid & 1;
    const int l15 = lane & 15, l4 = lane >> 4;
    const int arow = t >> 1, acol8 = (t & 1) * 8;   // 256 thr: each loads 2 short8 (rows 0..127, 2 chunks)
    f32x4 acc[4][4] = {};
    const short* Ash = (const short*)A;
    const short* Wsh = (const short*)WT;
    for (int kt = 0; kt < K / 32; ++kt) {
        short8 v0 = *(const short8*)(Ash + (size_t)(m0 + arow) * K + kt * 32 + acol8);
        short8 v1 = *(const short8*)(Ash + (size_t)(m0 + arow) * K + kt * 32 + acol8 + 16);
        __syncthreads();
        *(short8*)(&As[arow * LDS_STRIDE + acol8]) = v0;
        *(short8*)(&As[arow * LDS_STRIDE + acol8 + 16]) = v1;
        __syncthreads();
        short8 af[4], bfr[4];
#pragma unroll
        for (int mi = 0; mi < 4; ++mi)
            af[mi] = *(const short8*)(&As[(wr * 64 + mi * 16 + l15) * LDS_STRIDE + l4 * 8]);
#pragma unroll
        for (int ni = 0; ni < 4; ++ni)
            bfr[ni] = *(const short8*)(Wsh + (size_t)(n0 + wc * 64 + ni * 16 + l15) * K + kt * 32 + l4 * 8);
#pragma unroll
        for (int mi = 0; mi < 4; ++mi)
#pragma unroll
            for (int ni = 0; ni < 4; ++ni)
                acc[mi][ni] = __builtin_amdgcn_mfma_f32_16x16x32_bf16(af[mi], bfr[ni], acc[mi][ni], 0, 0, 0);
    }
    float bv[4];
    int col[4];
#pragma unroll
    for (int ni = 0; ni < 4; ++ni) {
        col[ni] = n0 + wc * 64 + ni * 16 + l15;
        bv[ni] = bias[col[ni]];
    }
    float csum[4] = {0, 0, 0, 0}, csq[4] = {0, 0, 0, 0};
    __hip_bfloat16* ob = (__hip_bfloat16*)outp;
    float* of = (float*)outp;
#pragma unroll
    for (int mi = 0; mi < 4; ++mi) {
#pragma unroll
        for (int r = 0; r < 4; ++r) {
            int rowg = m0 + wr * 64 + mi * 16 + l4 * 4 + r;  // D layout: row=(lane>>4)*4+reg
#pragma unroll
            for (int ni = 0; ni < 4; ++ni) {
                float v = fmaxf(acc[mi][ni][r] + bv[ni], 0.0f);
                if (OUT_BF16) ob[(size_t)rowg * HID + col[ni]] = __float2bfloat16(v);
                else          of[(size_t)rowg * HID + col[ni]] = v;
                csum[ni] += v;
                csq[ni] += v * v;
            }
        }
    }
#pragma unroll
    for (int ni = 0; ni < 4; ++ni) {
        float sv = csum[ni], q = csq[ni];
        sv += __shfl_xor(sv, 16); sv += __shfl_xor(sv, 32);
        q  += __shfl_xor(q, 16);  q  += __shfl_xor(q, 32);
        if (l4 == 0) {
            atomicAdd(&colsum[col[ni]], sv);
            atomicAdd(&colsq[col[ni]], q);
        }
    }
}

// ================= BN stats -> scale/shift =================
__global__ void finalize_kernel(const float* __restrict__ sum, const float* __restrict__ sq,
                                const float* __restrict__ g, const float* __restrict__ be,
                                float* __restrict__ scale, float* __restrict__ shift) {
    int c = threadIdx.x;
    float mu  = sum[c] * (1.0f / MROWS);
    float var = sq[c] * (1.0f / MROWS) - mu * mu;
    float inv = 1.0f / sqrtf(var + 1e-5f);
    float sc = g[c] * inv;
    scale[c] = sc;
    shift[c] = be[c] - mu * sc;
}

// ================= finalize BN1 + fold into W2 =================
__global__ __launch_bounds__(256) void foldw2_kernel(const float* __restrict__ W2,
                                                     const float* __restrict__ b2,
                                                     const float* __restrict__ sum1,
                                                     const float* __restrict__ sq1,
                                                     const float* __restrict__ g1,
                                                     const float* __restrict__ be1,
                                                     __hip_bfloat16* __restrict__ W2T,
                                                     float* __restrict__ bias2f) {
    __shared__ float red[256];
    const int n = blockIdx.x, k = threadIdx.x;
    float mu  = sum1[k] * (1.0f / MROWS);
    float var = sq1[k] * (1.0f / MROWS) - mu * mu;
    float scv = g1[k] / sqrtf(var + 1e-5f);
    float shv = be1[k] - mu * scv;
    float v = W2[(size_t)k * HID + n];
    W2T[(size_t)n * HID + k] = __float2bfloat16(scv * v);
    red[k] = shv * v;
    __syncthreads();
    for (int s = 128; s > 0; s >>= 1) {
        if (k < s) red[k] += red[k + s];
        __syncthreads();
    }
    if (k == 0) bias2f[n] = b2[n] + red[0];
}

// ================= final BN2 applied in place on d_out (fp32) =================
__global__ __launch_bounds__(256) void bn2_kernel(float* __restrict__ out,
                                                  const float* __restrict__ scale2,
                                                  const float* __restrict__ shift2) {
    int idx = blockIdx.x * blockDim.x + threadIdx.x;  // float4 index
    const int total = MROWS * HID / 4;
    for (; idx < total; idx += gridDim.x * blockDim.x) {
        float4 v = ((float4*)out)[idx];
        int c = (idx * 4) & (HID - 1);
        float4 sc = *(const float4*)(scale2 + c);
        float4 sh = *(const float4*)(shift2 + c);
        v.x = sc.x * v.x + sh.x;
        v.y = sc.y * v.y + sh.y;
        v.z = sc.z * v.z + sh.z;
        v.w = sc.w * v.w + sh.w;
        ((float4*)out)[idx] = v;
    }
}

extern "C" void kernel_launch(void* const* d_in, const int* in_sizes, int n_in,
                              void* d_out, int out_size, void* d_ws, size_t ws_size,
                              hipStream_t stream) {
    const float* x    = (const float*)d_in[0];
    const float* pos  = (const float*)d_in[1];
    const float* xs   = (const float*)d_in[3];
    const float* poss = (const float*)d_in[4];
    const float* W1   = (const float*)d_in[6];
    const float* b1   = (const float*)d_in[7];
    const float* g1   = (const float*)d_in[8];
    const float* be1  = (const float*)d_in[9];
    const float* W2   = (const float*)d_in[10];
    const float* b2   = (const float*)d_in[11];
    const float* g2   = (const float*)d_in[12];
    const float* be2  = (const float*)d_in[13];

    char* ws = (char*)d_ws;
    size_t off = 0;
    auto alloc = [&](size_t bytes) -> void* {
        void* p = ws + off;
        off += (bytes + 255) & ~(size_t)255;
        return p;
    };
    __hip_bfloat16* W1T   = (__hip_bfloat16*)alloc((size_t)HID * DIN * 2);
    __hip_bfloat16* W2T   = (__hip_bfloat16*)alloc((size_t)HID * HID * 2);
    float*          stats = (float*)alloc(4 * HID * sizeof(float));
    float *sum1 = stats, *sq1 = stats + HID, *sum2 = stats + 2 * HID, *sq2 = stats + 3 * HID;
    float* sc = (float*)alloc(3 * HID * sizeof(float));
    float *scale2 = sc, *shift2 = sc + HID, *bias2f = sc + 2 * HID;
    __hip_bfloat16* H0 = (__hip_bfloat16*)alloc((size_t)MROWS * DIN * 2);
    __hip_bfloat16* H1 = (__hip_bfloat16*)alloc((size_t)MROWS * HID * 2);

    knn_h_kernel<<<KNN_BLOCKS + WT_BLOCKS + 1, 256, 0, stream>>>(pos, poss, x, xs, W1, W1T, H0, stats);
    gemm_kernel<DIN, true><<<dim3(MROWS / 128, 2), 256, 0, stream>>>(H0, W1T, b1, H1, sum1, sq1);
    foldw2_kernel<<<HID, 256, 0, stream>>>(W2, b2, sum1, sq1, g1, be1, W2T, bias2f);
    gemm_kernel<HID, false><<<dim3(MROWS / 128, 2), 256, 0, stream>>>(H1, W2T, bias2f, d_out, sum2, sq2);
    finalize_kernel<<<1, 256, 0, stream>>>(sum2, sq2, g2, be2, scale2, shift2);
    bn2_kernel<<<2048, 256, 0, stream>>>((float*)d_out, scale2, shift2);
}

// Round 6
// 136.838 us; speedup vs baseline: 1.8784x; 1.0575x over previous
//
#include <hip/hip_runtime.h>
#include <hip/hip_bf16.h>

typedef __attribute__((ext_vector_type(8))) short short8;
typedef __attribute__((ext_vector_type(4))) float f32x4;
typedef __attribute__((ext_vector_type(2))) float f32x2;
typedef __attribute__((ext_vector_type(8))) float f32x8;

constexpr int BATCH  = 4;
constexpr int NSRC   = 2048;
constexpr int NTGT   = 8192;
constexpr int C_IN   = 256;
constexpr int C_SKIP = 128;
constexpr int DIN    = 384;   // C_IN + C_SKIP
constexpr int HID    = 256;
constexpr int MROWS  = BATCH * NTGT;  // 32768

constexpr int TGT_PER_BLK = 16;
constexpr int KNN_BLOCKS  = MROWS / TGT_PER_BLK;  // 2048
constexpr int WT_BLOCKS   = 8;                    // W1 transpose helper blocks
constexpr int LDS_STRIDE  = 36;                   // A-tile pad: spreads fragment reads across banks

// ================= fused KNN + interpolate + concat (+W1 transpose, +stats zero) =================
// 512 thr: 16 targets/block, 32 lanes/target; scan processes 2 sources/iter with packed-f32 math.
// __launch_bounds__(512,4): VGPR cap 128 -- never force a spill (R3 lesson); ~60 used -> 4 blk/CU anyway.
__global__ __launch_bounds__(512, 4) void knn_h_kernel(const float* __restrict__ pos,
                                                       const float* __restrict__ pos_skip,
                                                       const float* __restrict__ x,
                                                       const float* __restrict__ xs,
                                                       const float* __restrict__ W1,
                                                       __hip_bfloat16* __restrict__ W1T,
                                                       __hip_bfloat16* __restrict__ H0,
                                                       float* __restrict__ stats) {
#pragma clang fp contract(off)
    const int blk = blockIdx.x;
    if (blk >= KNN_BLOCKS) {
        const int e = blk - KNN_BLOCKS;
        if (e < WT_BLOCKS) {
            const int r  = e * 32 + (threadIdx.x >> 4);  // W1T row (output channel), 32 rows/block
            const int c0 = threadIdx.x & 15;
#pragma unroll
            for (int k = 0; k < DIN / 16; ++k) {
                int c = c0 + k * 16;
                W1T[(size_t)r * DIN + c] = __float2bfloat16(W1[(size_t)c * HID + r]);
            }
        } else {
            for (int i = threadIdx.x; i < 4 * HID; i += 512) stats[i] = 0.0f;
        }
        return;
    }
    __shared__ float4 sp[NSRC];
    __shared__ float  sd[TGT_PER_BLK][3];
    __shared__ int    si[TGT_PER_BLK][3];
    const int t0 = blk * TGT_PER_BLK;
    const int b  = t0 / NTGT;
    const float* ps = pos + (size_t)b * NSRC * 3;
    for (int j = threadIdx.x; j < NSRC; j += 512) {
        float X = ps[j * 3 + 0], Y = ps[j * 3 + 1], Z = ps[j * 3 + 2];
        float s2 = ((X * X) + (Y * Y)) + (Z * Z);
        sp[j] = make_float4(X, Y, Z, s2);
    }
    __syncthreads();
    const int g  = threadIdx.x >> 5;   // target group 0..15
    const int s  = threadIdx.x & 31;   // sub-lane 0..31
    const int tr = t0 + g;
    const float px = pos_skip[tr * 3 + 0], py = pos_skip[tr * 3 + 1], pz = pos_skip[tr * 3 + 2];
    const float pt2 = ((px * px) + (py * py)) + (pz * pz);
    const f32x2 px2 = {px, px}, py2 = {py, py}, pz2 = {pz, pz}, ptv = {pt2, pt2};
    float bd0 = 3e38f, bd1 = 3e38f, bd2 = 3e38f;
    int   bi0 = 0x7fffffff, bi1 = 0x7fffffff, bi2 = 0x7fffffff;
#pragma unroll 4
    for (int k = 0; k < NSRC / 64; ++k) {
        const int j1 = k * 64 + s;        // within-lane visit order is increasing j
        const int j2 = j1 + 32;
        float4 sa = sp[j1];
        float4 sb = sp[j2];
        f32x2 vx = {sa.x, sb.x}, vy = {sa.y, sb.y}, vz = {sa.z, sb.z}, vw = {sa.w, sb.w};
        // exact replica of reference's expanded formula: (pt2 + ps2) - 2*dot, contract(off) => no FMA
        f32x2 dot = ((px2 * vx) + (py2 * vy)) + (pz2 * vz);
        f32x2 d2v = (ptv + vw) - (f32x2{2.0f, 2.0f} * dot);
#pragma unroll
        for (int h = 0; h < 2; ++h) {
            float d2 = h == 0 ? d2v.x : d2v.y;
            int   j  = h == 0 ? j1 : j2;
            bool c0 = d2 < bd0, c1 = d2 < bd1, c2 = d2 < bd2;
            bd2 = c1 ? bd1 : (c2 ? d2 : bd2);  bi2 = c1 ? bi1 : (c2 ? j : bi2);
            bd1 = c0 ? bd0 : (c1 ? d2 : bd1);  bi1 = c0 ? bi0 : (c1 ? j : bi1);
            bd0 = c0 ? d2  : bd0;              bi0 = c0 ? j  : bi0;
        }
    }
    // butterfly merge across 32 sub-lanes; lex (d, idx) preserves reference tie-break
#pragma unroll
    for (int m = 1; m <= 16; m <<= 1) {
        float od0 = __shfl_xor(bd0, m), od1 = __shfl_xor(bd1, m), od2 = __shfl_xor(bd2, m);
        int   oi0 = __shfl_xor(bi0, m), oi1 = __shfl_xor(bi1, m), oi2 = __shfl_xor(bi2, m);
#pragma unroll
        for (int e = 0; e < 3; ++e) {
            float d = e == 0 ? od0 : (e == 1 ? od1 : od2);
            int   i = e == 0 ? oi0 : (e == 1 ? oi1 : oi2);
            bool c0 = (d < bd0) || (d == bd0 && i < bi0);
            bool c1 = (d < bd1) || (d == bd1 && i < bi1);
            bool c2 = (d < bd2) || (d == bd2 && i < bi2);
            bd2 = c1 ? bd1 : (c2 ? d : bd2);  bi2 = c1 ? bi1 : (c2 ? i : bi2);
            bd1 = c0 ? bd0 : (c1 ? d : bd1);  bi1 = c0 ? bi0 : (c1 ? i : bi1);
            bd0 = c0 ? d   : bd0;             bi0 = c0 ? i  : bi0;
        }
    }
    if (s == 0) {
        sd[g][0] = bd0; sd[g][1] = bd1; sd[g][2] = bd2;
        si[g][0] = bi0; si[g][1] = bi1; si[g][2] = bi2;
    }
    __syncthreads();
    // gather + concat phase: 8 waves x 2 targets, 64-lane coalesced columns
    const int w = threadIdx.x >> 6, lane = threadIdx.x & 63;
    const float* xb = x + (size_t)b * NSRC * C_IN;
#pragma unroll
    for (int u = 0; u < 2; ++u) {
        const int tt = w * 2 + u;
        const int r  = t0 + tt;
        float w0 = 1.0f / fmaxf(sd[tt][0], 1e-16f);
        float w1 = 1.0f / fmaxf(sd[tt][1], 1e-16f);
        float w2 = 1.0f / fmaxf(sd[tt][2], 1e-16f);
        float inv = 1.0f / ((w0 + w1) + w2);
        const float* f0 = xb + (size_t)si[tt][0] * C_IN;
        const float* f1 = xb + (size_t)si[tt][1] * C_IN;
        const float* f2 = xb + (size_t)si[tt][2] * C_IN;
        __hip_bfloat16* o = H0 + (size_t)r * DIN;
#pragma unroll
        for (int kk = 0; kk < 4; ++kk) {
            int c = lane + kk * 64;
            float v = ((w0 * f0[c] + w1 * f1[c]) + w2 * f2[c]) * inv;
            o[c] = __float2bfloat16(v);
        }
        const float* srow = xs + (size_t)r * C_SKIP;
#pragma unroll
        for (int kk = 0; kk < 2; ++kk) {
            int c = lane + kk * 64;
            o[C_IN + c] = __float2bfloat16(srow[c]);
        }
    }
}

// ================= GEMM: out = relu(A@W + bias) (bf16), plus column sum/sumsq =================
// A: [MROWS][K] bf16; WT: [HID][K] bf16. 256 thr = 4 waves; tile = 128 rows x FULL N=256
// (A fetched once). Wave w: rows (w&1)*64, cols (w>>1)*128 -> acc[4][8] = 128 VGPRs.
// __launch_bounds__(256,1): VGPR cap 512 -> guaranteed no spill (R3 lesson); ~210 needed -> 2 blocks/CU.
template <int K>
__global__ __launch_bounds__(256, 1) void gemm_kernel(const __hip_bfloat16* __restrict__ A,
                                                      const __hip_bfloat16* __restrict__ WT,
                                                      const float* __restrict__ bias,
                                                      __hip_bfloat16* __restrict__ outp,
                                                      float* __restrict__ colsum,
                                                      float* __restrict__ colsq) {
    __shared__ short As[128 * LDS_STRIDE];
    const int t = threadIdx.x;
    const int m0 = blockIdx.x * 128;
    const int wid = t >> 6, lane = t & 63;
    const int wr = wid & 1, wcq = wid >> 1;           // row half, col half
    const int l15 = lane & 15, l4 = lane >> 4;
    const int arow = t >> 1, acol8 = (t & 1) * 8;     // staging: 2 short8 per thread
    f32x4 acc[4][8] = {};
    const short* Ash = (const short*)A;
    const short* Wsh = (const short*)WT;
    for (int kt = 0; kt < K / 32; ++kt) {
        short8 v0 = *(const short8*)(Ash + (size_t)(m0 + arow) * K + kt * 32 + acol8);
        short8 v1 = *(const short8*)(Ash + (size_t)(m0 + arow) * K + kt * 32 + acol8 + 16);
        __syncthreads();
        *(short8*)(&As[arow * LDS_STRIDE + acol8]) = v0;
        *(short8*)(&As[arow * LDS_STRIDE + acol8 + 16]) = v1;
        __syncthreads();
        short8 af[4], bfr[8];
#pragma unroll
        for (int mi = 0; mi < 4; ++mi)
            af[mi] = *(const short8*)(&As[(wr * 64 + mi * 16 + l15) * LDS_STRIDE + l4 * 8]);
#pragma unroll
        for (int ni = 0; ni < 8; ++ni)
            bfr[ni] = *(const short8*)(Wsh + (size_t)(wcq * 128 + ni * 16 + l15) * K + kt * 32 + l4 * 8);
#pragma unroll
        for (int mi = 0; mi < 4; ++mi)
#pragma unroll
            for (int ni = 0; ni < 8; ++ni)
                acc[mi][ni] = __builtin_amdgcn_mfma_f32_16x16x32_bf16(af[mi], bfr[ni], acc[mi][ni], 0, 0, 0);
    }
    float bv[8];
    int col[8];
#pragma unroll
    for (int ni = 0; ni < 8; ++ni) {
        col[ni] = wcq * 128 + ni * 16 + l15;
        bv[ni] = bias[col[ni]];
    }
    float csum[8] = {}, csq[8] = {};
#pragma unroll
    for (int mi = 0; mi < 4; ++mi) {
#pragma unroll
        for (int r = 0; r < 4; ++r) {
            int rowg = m0 + wr * 64 + mi * 16 + l4 * 4 + r;  // D layout: row=(lane>>4)*4+reg
#pragma unroll
            for (int ni = 0; ni < 8; ++ni) {
                float v = fmaxf(acc[mi][ni][r] + bv[ni], 0.0f);
                outp[(size_t)rowg * HID + col[ni]] = __float2bfloat16(v);
                csum[ni] += v;
                csq[ni] += v * v;
            }
        }
    }
#pragma unroll
    for (int ni = 0; ni < 8; ++ni) {
        float sv = csum[ni], q = csq[ni];
        sv += __shfl_xor(sv, 16); sv += __shfl_xor(sv, 32);
        q  += __shfl_xor(q, 16);  q  += __shfl_xor(q, 32);
        if (l4 == 0) {
            atomicAdd(&colsum[col[ni]], sv);
            atomicAdd(&colsq[col[ni]], q);
        }
    }
}

// ================= finalize BN1 + fold into W2 =================
__global__ __launch_bounds__(256) void foldw2_kernel(const float* __restrict__ W2,
                                                     const float* __restrict__ b2,
                                                     const float* __restrict__ sum1,
                                                     const float* __restrict__ sq1,
                                                     const float* __restrict__ g1,
                                                     const float* __restrict__ be1,
                                                     __hip_bfloat16* __restrict__ W2T,
                                                     float* __restrict__ bias2f) {
    __shared__ float red[256];
    const int n = blockIdx.x, k = threadIdx.x;
    float mu  = sum1[k] * (1.0f / MROWS);
    float var = sq1[k] * (1.0f / MROWS) - mu * mu;
    float scv = g1[k] / sqrtf(var + 1e-5f);
    float shv = be1[k] - mu * scv;
    float v = W2[(size_t)k * HID + n];
    W2T[(size_t)n * HID + k] = __float2bfloat16(scv * v);
    red[k] = shv * v;
    __syncthreads();
    for (int s = 128; s > 0; s >>= 1) {
        if (k < s) red[k] += red[k + s];
        __syncthreads();
    }
    if (k == 0) bias2f[n] = b2[n] + red[0];
}

// ================= BN2: read h2 (bf16), apply scale/shift (computed in-block), write fp32 =================
__global__ __launch_bounds__(256) void bn2_kernel(const __hip_bfloat16* __restrict__ h2,
                                                  const float* __restrict__ sum2,
                                                  const float* __restrict__ sq2,
                                                  const float* __restrict__ g2,
                                                  const float* __restrict__ be2,
                                                  float* __restrict__ out) {
    __shared__ float lsc[HID], lsh[HID];
    {
        int c = threadIdx.x;
        float mu  = sum2[c] * (1.0f / MROWS);
        float var = sq2[c] * (1.0f / MROWS) - mu * mu;
        float scv = g2[c] / sqrtf(var + 1e-5f);
        lsc[c] = scv;
        lsh[c] = be2[c] - mu * scv;
    }
    __syncthreads();
    int idx = blockIdx.x * blockDim.x + threadIdx.x;  // 8-element chunk index
    const int total = MROWS * HID / 8;
    for (; idx < total; idx += gridDim.x * blockDim.x) {
        short8 v = *(const short8*)(h2 + (size_t)idx * 8);
        int c = (idx * 8) & (HID - 1);
        f32x8 o;   // single ext-vector, constant-indexed below (R5 bug: two float4s + OOB ptr walk)
#pragma unroll
        for (int e = 0; e < 8; ++e) {
            float f = __uint_as_float(((unsigned)(unsigned short)v[e]) << 16);
            o[e] = lsc[c + e] * f + lsh[c + e];
        }
        *(f32x8*)(out + (size_t)idx * 8) = o;
    }
}

extern "C" void kernel_launch(void* const* d_in, const int* in_sizes, int n_in,
                              void* d_out, int out_size, void* d_ws, size_t ws_size,
                              hipStream_t stream) {
    const float* x    = (const float*)d_in[0];
    const float* pos  = (const float*)d_in[1];
    const float* xs   = (const float*)d_in[3];
    const float* poss = (const float*)d_in[4];
    const float* W1   = (const float*)d_in[6];
    const float* b1   = (const float*)d_in[7];
    const float* g1   = (const float*)d_in[8];
    const float* be1  = (const float*)d_in[9];
    const float* W2   = (const float*)d_in[10];
    const float* b2   = (const float*)d_in[11];
    const float* g2   = (const float*)d_in[12];
    const float* be2  = (const float*)d_in[13];

    char* ws = (char*)d_ws;
    size_t off = 0;
    auto alloc = [&](size_t bytes) -> void* {
        void* p = ws + off;
        off += (bytes + 255) & ~(size_t)255;
        return p;
    };
    __hip_bfloat16* W1T   = (__hip_bfloat16*)alloc((size_t)HID * DIN * 2);
    __hip_bfloat16* W2T   = (__hip_bfloat16*)alloc((size_t)HID * HID * 2);
    float*          stats = (float*)alloc(4 * HID * sizeof(float));
    float *sum1 = stats, *sq1 = stats + HID, *sum2 = stats + 2 * HID, *sq2 = stats + 3 * HID;
    float*          bias2f = (float*)alloc(HID * sizeof(float));
    __hip_bfloat16* H0 = (__hip_bfloat16*)alloc((size_t)MROWS * DIN * 2);
    __hip_bfloat16* H1 = (__hip_bfloat16*)alloc((size_t)MROWS * HID * 2);
    __hip_bfloat16* H2 = H0;  // H0 dead after gemm1; reuse for gemm2 output

    knn_h_kernel<<<KNN_BLOCKS + WT_BLOCKS + 1, 512, 0, stream>>>(pos, poss, x, xs, W1, W1T, H0, stats);
    gemm_kernel<DIN><<<MROWS / 128, 256, 0, stream>>>(H0, W1T, b1, H1, sum1, sq1);
    foldw2_kernel<<<HID, 256, 0, stream>>>(W2, b2, sum1, sq1, g1, be1, W2T, bias2f);
    gemm_kernel<HID><<<MROWS / 128, 256, 0, stream>>>(H1, W2T, bias2f, H2, sum2, sq2);
    bn2_kernel<<<1024, 256, 0, stream>>>(H2, sum2, sq2, g2, be2, (float*)d_out);
}